// Round 2
// baseline (1512.869 us; speedup 1.0000x reference)
//
#include <hip/hip_runtime.h>
#include <math.h>

typedef unsigned int u32;
typedef unsigned long long u64;
typedef float f32x4 __attribute__((ext_vector_type(4)));

#define NQ     1000000
#define KRANK  499999u
#define NS     16384        // samples per group
#define RANK_LO 7680u       // 8192 - 512  (8-sigma bracket)
#define RANK_HI 8704u       // 8192 + 512
#define CAP    131072       // candidate capacity per group (expected ~62K)
#define LCAP   256          // per-block LDS staging per group (expected ~61)
#define CHUNK_STRIDE 15625  // NQ / 64 chunks
#define MAIN_BLOCKS 1024

// ---- ws layout (bytes) ----
#define OFF_STD    0            // 4M floats = 16,000,000
#define OFF_CAND   16000000     // 24*131072*4 = 12,582,912 -> ends 28,582,912
#define OFF_KLO    28582912     // 24*4
#define OFF_KHI    28583008     // 24*4
#define OFF_GCNT   28583104     // 24*4 (zeroed)
#define OFF_CNTLO  28583200     // 24*4 (zeroed)
#define OFF_FLAG   28583296     // 24*4 (zeroed)
#define OFF_SELVAL 28583392     // 24*4
#define OFF_TABLE  28583488     // 640*4 = 2560 (16B aligned)
#define ZERO_BYTES 288          // gcnt + cntlo + flag

__device__ __forceinline__ u32 fkey(float x) {
  u32 b = __float_as_uint(x);
  return (b & 0x80000000u) ? ~b : (b | 0x80000000u);
}
__device__ __forceinline__ float funkey(u32 u) {
  u32 b = (u & 0x80000000u) ? (u & 0x7fffffffu) : ~u;
  return __uint_as_float(b);
}
__device__ __forceinline__ void nt_store4(float4* p, float4 v) {
  f32x4 w = {v.x, v.y, v.z, v.w};
  __builtin_nontemporal_store(w, (f32x4*)p);
}
// ddof=1 std over 10 values — identical op order everywhere it is used.
__device__ __forceinline__ float std10(const float* v) {
  float sum = 0.f;
  #pragma unroll
  for (int b = 0; b < 10; ++b) sum = __fadd_rn(sum, v[b]);
  float mean = __fdiv_rn(sum, 10.0f);
  float ssd = 0.f;
  #pragma unroll
  for (int b = 0; b < 10; ++b) {
    float d = __fsub_rn(v[b], mean);
    ssd = __fadd_rn(ssd, __fmul_rn(d, d));
  }
  return sqrtf(__fdiv_rn(ssd, 9.0f));
}

// K0: 16-pattern x 10-batch x 4 output table. out only depends on mode pattern.
__global__ void k_table(const float* __restrict__ x, const float* __restrict__ dptr,
                        float* __restrict__ table) {
  int t = threadIdx.x;
  if (t >= 160) return;
  int pat = t / 10, b = t % 10;
  float delta = *dptr;
  float xs[4];
  xs[0] = 0.f; xs[1] = x[b*3]; xs[2] = x[b*3+1]; xs[3] = x[b*3+2];
  float dx[4];
  #pragma unroll
  for (int j = 0; j < 4; ++j) dx[j] = delta * (float)((pat >> j) & 1) + xs[j];
  #pragma unroll
  for (int i = 0; i < 4; ++i) {
    float m = -1e30f;
    #pragma unroll
    for (int j = 0; j < 4; ++j) if (j != i) m = fmaxf(m, dx[j]);
    float ssum = 0.f;
    #pragma unroll
    for (int j = 0; j < 4; ++j) if (j != i) ssum += expf(dx[j] - m);
    table[(pat*10 + b)*4 + i] = dx[i] - (logf(ssum) + m);
  }
}

// K1: per-group pivot estimation from a deterministic 16384-element sample.
// Groups 0..19: logits (b=g/4, i=g%4). Groups 20..23: std over b of column i.
// Two exact radix selects over LDS-resident sample keys -> klo (rank 7680),
// khi (rank 8704). Bracket is +-8 sigma of the order-statistic rank error.
__global__ __launch_bounds__(256) void k_sample(const float* __restrict__ logits,
                                                u32* __restrict__ kloA,
                                                u32* __restrict__ khiA) {
  __shared__ u32 keys[NS];
  __shared__ u32 hist[256], sdx[256];
  __shared__ u32 sh_bin, sh_k;
  int g = blockIdx.x, t = threadIdx.x;
  if (g < 20) {
    int b = g >> 2, i = g & 3;
    const float* base = logits + (size_t)b * NQ * 4 + i;
    for (int s = t; s < NS; s += 256) {
      int n = (s >> 8) * CHUNK_STRIDE + (s & 255);
      keys[s] = fkey(base[(size_t)n * 4]);
    }
  } else {
    int i = g - 20;
    const float* base = logits + i;
    for (int s = t; s < NS; s += 256) {
      int n = (s >> 8) * CHUNK_STRIDE + (s & 255);
      float tmp[10];
      #pragma unroll
      for (int b = 0; b < 10; ++b) tmp[b] = base[((size_t)b * NQ + n) * 4];
      keys[s] = fkey(std10(tmp));
    }
  }
  __syncthreads();
  #pragma unroll
  for (int which = 0; which < 2; ++which) {
    u32 k = which ? RANK_HI : RANK_LO;
    u32 pfx = 0;
    for (int rnd = 0; rnd < 4; ++rnd) {
      int sh = 24 - 8 * rnd;
      hist[t] = 0;
      __syncthreads();
      for (int s = t; s < NS; s += 256) {
        u32 u = keys[s];
        if (rnd == 0 || (u >> (sh + 8)) == pfx)
          atomicAdd(&hist[(u >> sh) & 255u], 1u);
      }
      __syncthreads();
      u32 part = hist[t];
      sdx[t] = part;
      __syncthreads();
      for (int off = 1; off < 256; off <<= 1) {
        u32 y = (t >= off) ? sdx[t - off] : 0u;
        __syncthreads();
        sdx[t] += y;
        __syncthreads();
      }
      u32 incl = sdx[t], excl = incl - part;
      if (k >= excl && k < incl) { sh_bin = (u32)t; sh_k = k - excl; }
      __syncthreads();
      pfx = (pfx << 8) | sh_bin;
      k = sh_k;
      __syncthreads();
    }
    if (t == 0) { if (which) khiA[g] = pfx; else kloA[g] = pfx; }
    __syncthreads();
  }
}

// K2: the ONLY full pass over logits. Computes std (writes stdv), and for all
// 24 groups: count of keys < klo (register counters, wave-reduced), plus
// compaction of bracket hits [klo,khi) into cand via small LDS staging
// (one global atomic per group per block). No histograms, no hot-bin atomics.
__global__ __launch_bounds__(256) void k_main(const float* __restrict__ logits,
                                              float* __restrict__ stdv,
                                              const u32* __restrict__ kloA,
                                              const u32* __restrict__ khiA,
                                              u32* __restrict__ gcnt,
                                              u32* __restrict__ cntlo,
                                              u32* __restrict__ cand) {
  __shared__ u32 lcnt[24];
  __shared__ u32 lbase[24];
  __shared__ u32 lbuf[24 * LCAP];
  int t = threadIdx.x;
  if (t < 24) lcnt[t] = 0;
  __syncthreads();
  u32 klo[24], khi[24];
  #pragma unroll
  for (int g = 0; g < 24; ++g) { klo[g] = kloA[g]; khi[g] = khiA[g]; }
  u32 cnt[24];
  #pragma unroll
  for (int g = 0; g < 24; ++g) cnt[g] = 0;
  const float4* L = (const float4*)logits;
  float4* S = (float4*)stdv;
  for (int q = blockIdx.x * 256 + t; q < NQ; q += MAIN_BLOCKS * 256) {
    float4 v[10];
    #pragma unroll
    for (int b = 0; b < 10; ++b) v[b] = L[(size_t)b * NQ + q];
    float4 r;
    #pragma unroll
    for (int j = 0; j < 4; ++j) {
      float tmp[10];
      #pragma unroll
      for (int b = 0; b < 10; ++b) tmp[b] = ((const float*)&v[b])[j];
      float sdev = std10(tmp);
      ((float*)&r)[j] = sdev;
      u32 u = fkey(sdev);
      {
        int g = 20 + j;
        cnt[g] += (u < klo[g]) ? 1u : 0u;
        if (u >= klo[g] && u < khi[g]) {
          u32 p = atomicAdd(&lcnt[g], 1u);
          if (p < LCAP) lbuf[g * LCAP + p] = u;
          else { u32 gp = atomicAdd(&gcnt[g], 1u); if (gp < CAP) cand[(size_t)g * CAP + gp] = u; }
        }
      }
      #pragma unroll
      for (int b = 0; b < 5; ++b) {
        u32 w = fkey(tmp[b]);
        int gg = b * 4 + j;
        cnt[gg] += (w < klo[gg]) ? 1u : 0u;
        if (w >= klo[gg] && w < khi[gg]) {
          u32 p = atomicAdd(&lcnt[gg], 1u);
          if (p < LCAP) lbuf[gg * LCAP + p] = w;
          else { u32 gp = atomicAdd(&gcnt[gg], 1u); if (gp < CAP) cand[(size_t)gg * CAP + gp] = w; }
        }
      }
    }
    nt_store4(&S[q], r);
  }
  // wave-reduce below-pivot counters, one global atomic per wave per group
  #pragma unroll
  for (int g = 0; g < 24; ++g) {
    int c = (int)cnt[g];
    #pragma unroll
    for (int off = 32; off > 0; off >>= 1) c += __shfl_down(c, off, 64);
    if ((t & 63) == 0 && c) atomicAdd(&cntlo[g], (u32)c);
  }
  __syncthreads();
  // flush staged candidates: one gcnt atomic per group per block
  if (t < 24) {
    u32 cnum = lcnt[t];
    if (cnum > LCAP) cnum = LCAP;
    lbase[t] = cnum ? atomicAdd(&gcnt[t], cnum) : 0u;
    lcnt[t] = cnum;
  }
  __syncthreads();
  for (int g = 0; g < 24; ++g) {
    u32 cnum = lcnt[g], base = lbase[g];
    for (u32 i = t; i < cnum; i += 256) {
      u32 idx = base + i;
      if (idx < CAP) cand[(size_t)g * CAP + idx] = lbuf[g * LCAP + i];
    }
  }
}

// K3: exact radix select of rank (KRANK - cntlo) among the compacted
// candidates. Starts at the first byte where klo and khi-1 differ (all
// candidates share the common prefix). Sets flag on any bracket failure.
__global__ __launch_bounds__(256) void k_sel(const u32* __restrict__ cand,
                                             const u32* __restrict__ gcnt,
                                             const u32* __restrict__ cntlo,
                                             const u32* __restrict__ kloA,
                                             const u32* __restrict__ khiA,
                                             float* __restrict__ selval,
                                             u32* __restrict__ flag) {
  int g = blockIdx.x, t = threadIdx.x;
  u32 n = gcnt[g];
  u32 k = KRANK - cntlo[g];      // underflow -> huge -> caught below
  if (n == 0 || n > CAP || k >= n) { if (t == 0) flag[g] = 1; return; }
  u32 lo = kloA[g], hi1 = khiA[g] - 1u;
  u32 xx = lo ^ hi1;
  int hb = xx ? (31 - __clz((int)xx)) : 0;
  int startRnd = 3 - (hb >> 3);
  __shared__ u32 hist[256], sdx[256];
  __shared__ u32 sh_bin, sh_k;
  const u32* c = cand + (size_t)g * CAP;
  u32 pfx = (startRnd == 0) ? 0u : (lo >> (32 - 8 * startRnd));
  for (int rnd = startRnd; rnd < 4; ++rnd) {
    int sh = 24 - 8 * rnd;
    hist[t] = 0;
    __syncthreads();
    for (u32 i = t; i < n; i += 256) {
      u32 u = c[i];
      if (rnd == 0 || (u >> (sh + 8)) == pfx)
        atomicAdd(&hist[(u >> sh) & 255u], 1u);
    }
    __syncthreads();
    u32 part = hist[t];
    sdx[t] = part;
    __syncthreads();
    for (int off = 1; off < 256; off <<= 1) {
      u32 y = (t >= off) ? sdx[t - off] : 0u;
      __syncthreads();
      sdx[t] += y;
      __syncthreads();
    }
    u32 incl = sdx[t], excl = incl - part;
    if (k >= excl && k < incl) { sh_bin = (u32)t; sh_k = k - excl; }
    __syncthreads();
    pfx = (pfx << 8) | sh_bin;
    k = sh_k;
    __syncthreads();
  }
  if (t == 0) selval[g] = funkey(pfx);
}

// K4: correctness fallback — exact full-column radix select for any group
// whose bracket failed. Early-exits (never runs for random-normal data).
__global__ __launch_bounds__(256) void k_fallback(const float* __restrict__ logits,
                                                  const float* __restrict__ stdv,
                                                  const u32* __restrict__ flag,
                                                  float* __restrict__ selval) {
  int g = blockIdx.x, t = threadIdx.x;
  if (!flag[g]) return;
  const float* base = (g < 20) ? (logits + (size_t)(g >> 2) * NQ * 4 + (g & 3))
                               : (stdv + (g - 20));
  __shared__ u32 hist[256], sdx[256];
  __shared__ u32 sh_bin, sh_k;
  u32 pfx = 0, k = KRANK;
  for (int rnd = 0; rnd < 4; ++rnd) {
    int sh = 24 - 8 * rnd;
    hist[t] = 0;
    __syncthreads();
    for (int i = t; i < NQ; i += 256) {
      u32 u = fkey(base[(size_t)i * 4]);
      if (rnd == 0 || (u >> (sh + 8)) == pfx)
        atomicAdd(&hist[(u >> sh) & 255u], 1u);
    }
    __syncthreads();
    u32 part = hist[t];
    sdx[t] = part;
    __syncthreads();
    for (int off = 1; off < 256; off <<= 1) {
      u32 y = (t >= off) ? sdx[t - off] : 0u;
      __syncthreads();
      sdx[t] += y;
      __syncthreads();
    }
    u32 incl = sdx[t], excl = incl - part;
    if (k >= excl && k < incl) { sh_bin = (u32)t; sh_k = k - excl; }
    __syncthreads();
    pfx = (pfx << 8) | sh_bin;
    k = sh_k;
    __syncthreads();
  }
  if (t == 0) selval[g] = funkey(pfx);
}

// K5: fused mode + out + c. thr = max(med+1.96*std_med, med+delta/2) gives
// identical booleans to the two-compare form for non-NaN data. NT stores.
__global__ __launch_bounds__(256) void k_final(const float* __restrict__ logits,
                                               const float* __restrict__ selval,
                                               const float* __restrict__ table,
                                               const float* __restrict__ dptr,
                                               float* __restrict__ out) {
  __shared__ float thr[20];
  __shared__ float4 tab[160];
  int t = threadIdx.x;
  if (t < 20) {
    float m  = selval[t];
    float sm = selval[20 + (t & 3)];
    float a = __fadd_rn(m, __fmul_rn(1.96f, sm));   // two roundings, no FMA
    float b = __fadd_rn(m, __fmul_rn(0.5f, *dptr));
    thr[t] = fmaxf(a, b);
  }
  if (t < 160) tab[t] = ((const float4*)table)[t];
  __syncthreads();
  const float4* L = (const float4*)logits;
  float4* O = (float4*)out;
  float4* C = O + 10 * NQ;
  for (int n = blockIdx.x * 256 + t; n < NQ; n += gridDim.x * 256) {
    int s0 = 0, s1 = 0, s2 = 0, s3 = 0;
    #pragma unroll
    for (int b = 0; b < 5; ++b) {
      float4 v = L[b * NQ + n];
      s0 += v.x >= thr[b*4+0];
      s1 += v.y >= thr[b*4+1];
      s2 += v.z >= thr[b*4+2];
      s3 += v.w >= thr[b*4+3];
    }
    int m0 = s0 >= 3, m1 = s1 >= 3, m2 = s2 >= 3, m3 = s3 >= 3;
    int pat = m0 | (m1 << 1) | (m2 << 2) | (m3 << 3);
    float4 cm = make_float4((float)m0, (float)m1, (float)m2, (float)m3);
    #pragma unroll
    for (int b = 0; b < 10; ++b) {
      nt_store4(&O[b * NQ + n], tab[pat * 10 + b]);
      nt_store4(&C[b * NQ + n], cm);
    }
  }
}

extern "C" void kernel_launch(void* const* d_in, const int* in_sizes, int n_in,
                              void* d_out, int out_size, void* d_ws, size_t ws_size,
                              hipStream_t stream) {
  const float* logits = (const float*)d_in[0];
  const float* x      = (const float*)d_in[1];
  const float* dptr   = (const float*)d_in[2];
  float* out = (float*)d_out;
  char* ws = (char*)d_ws;

  float* stdv   = (float*)(ws + OFF_STD);
  u32*   cand   = (u32*)(ws + OFF_CAND);
  u32*   klo    = (u32*)(ws + OFF_KLO);
  u32*   khi    = (u32*)(ws + OFF_KHI);
  u32*   gcnt   = (u32*)(ws + OFF_GCNT);
  u32*   cntlo  = (u32*)(ws + OFF_CNTLO);
  u32*   flag   = (u32*)(ws + OFF_FLAG);
  float* selval = (float*)(ws + OFF_SELVAL);
  float* table  = (float*)(ws + OFF_TABLE);

  hipMemsetAsync(ws + OFF_GCNT, 0, ZERO_BYTES, stream);

  k_table<<<dim3(1), dim3(192), 0, stream>>>(x, dptr, table);
  k_sample<<<dim3(24), dim3(256), 0, stream>>>(logits, klo, khi);
  k_main<<<dim3(MAIN_BLOCKS), dim3(256), 0, stream>>>(logits, stdv, klo, khi, gcnt, cntlo, cand);
  k_sel<<<dim3(24), dim3(256), 0, stream>>>(cand, gcnt, cntlo, klo, khi, selval, flag);
  k_fallback<<<dim3(24), dim3(256), 0, stream>>>(logits, stdv, flag, selval);
  k_final<<<dim3(2048), dim3(256), 0, stream>>>(logits, selval, table, dptr, out);
}

// Round 5
// 1010.114 us; speedup vs baseline: 1.4977x; 1.4977x over previous
//
#include <hip/hip_runtime.h>
#include <math.h>

typedef unsigned int u32;
typedef unsigned long long u64;
typedef float f32x4 __attribute__((ext_vector_type(4)));

#define NQ     1000000
#define KRANK  499999u
#define NS     16384        // samples per group
#define RANK_LO 7680u       // 8192 - 512  (8-sigma bracket)
#define RANK_HI 8704u       // 8192 + 512
#define CAP    131072       // candidate capacity per group (expected ~62K)
#define LCAP_S 256          // k_std per-block LDS staging per std group (expect ~61)
#define LCAP_C 1024         // k_cnt per-block LDS staging per logit group (expect ~490)
#define CHUNK_STRIDE 15625
#define BPS_C  128          // blocks per slice in k_cnt

// ---- ws layout (bytes) ----
#define OFF_STD    0            // 4M floats = 16,000,000
#define OFF_CAND   16000000     // 24*131072*4 = 12,582,912 -> ends 28,582,912
#define OFF_KLO    28582912     // 24*4
#define OFF_KHI    28583008     // 24*4
#define OFF_GCNT   28583104     // 24*4 (zeroed)
#define OFF_CNTLO  28583200     // 24*4 (zeroed)
#define OFF_FLAG   28583296     // 24*4 (zeroed)
#define OFF_SELVAL 28583392     // 24*4
#define OFF_TABLE  28583488     // 640*4 = 2560 (16B aligned)
#define ZERO_BYTES 288          // gcnt + cntlo + flag (contiguous)

__device__ __forceinline__ u32 fkey(float x) {
  u32 b = __float_as_uint(x);
  return (b & 0x80000000u) ? ~b : (b | 0x80000000u);
}
__device__ __forceinline__ float funkey(u32 u) {
  u32 b = (u & 0x80000000u) ? (u & 0x7fffffffu) : ~u;
  return __uint_as_float(b);
}
__device__ __forceinline__ void nt_store4(float4* p, float4 v) {
  f32x4 w = {v.x, v.y, v.z, v.w};
  __builtin_nontemporal_store(w, (f32x4*)p);
}
// ddof=1 std over 10 values — identical op order everywhere it is used.
__device__ __forceinline__ float std10(const float* v) {
  float sum = 0.f;
  #pragma unroll
  for (int b = 0; b < 10; ++b) sum = __fadd_rn(sum, v[b]);
  float mean = __fdiv_rn(sum, 10.0f);
  float ssd = 0.f;
  #pragma unroll
  for (int b = 0; b < 10; ++b) {
    float d = __fsub_rn(v[b], mean);
    ssd = __fadd_rn(ssd, __fmul_rn(d, d));
  }
  return sqrtf(__fdiv_rn(ssd, 9.0f));
}

// K0: 16-pattern x 10-batch x 4 output table.
__global__ void k_table(const float* __restrict__ x, const float* __restrict__ dptr,
                        float* __restrict__ table) {
  int t = threadIdx.x;
  if (t >= 160) return;
  int pat = t / 10, b = t % 10;
  float delta = *dptr;
  float xs[4];
  xs[0] = 0.f; xs[1] = x[b*3]; xs[2] = x[b*3+1]; xs[3] = x[b*3+2];
  float dx[4];
  #pragma unroll
  for (int j = 0; j < 4; ++j) dx[j] = delta * (float)((pat >> j) & 1) + xs[j];
  #pragma unroll
  for (int i = 0; i < 4; ++i) {
    float m = -1e30f;
    #pragma unroll
    for (int j = 0; j < 4; ++j) if (j != i) m = fmaxf(m, dx[j]);
    float ssum = 0.f;
    #pragma unroll
    for (int j = 0; j < 4; ++j) if (j != i) ssum += expf(dx[j] - m);
    table[(pat*10 + b)*4 + i] = dx[i] - (logf(ssum) + m);
  }
}

// K1: pivot estimation from deterministic 16384-element sample per group.
// (correctness-proven round 2)
__global__ __launch_bounds__(256) void k_sample(const float* __restrict__ logits,
                                                u32* __restrict__ kloA,
                                                u32* __restrict__ khiA) {
  __shared__ u32 keys[NS];
  __shared__ u32 hist[256], sdx[256];
  __shared__ u32 sh_bin, sh_k;
  int g = blockIdx.x, t = threadIdx.x;
  if (g < 20) {
    int b = g >> 2, i = g & 3;
    const float* base = logits + (size_t)b * NQ * 4 + i;
    for (int s = t; s < NS; s += 256) {
      int n = (s >> 8) * CHUNK_STRIDE + (s & 255);
      keys[s] = fkey(base[(size_t)n * 4]);
    }
  } else {
    int i = g - 20;
    const float* base = logits + i;
    for (int s = t; s < NS; s += 256) {
      int n = (s >> 8) * CHUNK_STRIDE + (s & 255);
      float tmp[10];
      #pragma unroll
      for (int b = 0; b < 10; ++b) tmp[b] = base[((size_t)b * NQ + n) * 4];
      keys[s] = fkey(std10(tmp));
    }
  }
  __syncthreads();
  #pragma unroll
  for (int which = 0; which < 2; ++which) {
    u32 k = which ? RANK_HI : RANK_LO;
    u32 pfx = 0;
    for (int rnd = 0; rnd < 4; ++rnd) {
      int sh = 24 - 8 * rnd;
      hist[t] = 0;
      __syncthreads();
      for (int s = t; s < NS; s += 256) {
        u32 u = keys[s];
        if (rnd == 0 || (u >> (sh + 8)) == pfx)
          atomicAdd(&hist[(u >> sh) & 255u], 1u);
      }
      __syncthreads();
      u32 part = hist[t];
      sdx[t] = part;
      __syncthreads();
      for (int off = 1; off < 256; off <<= 1) {
        u32 y = (t >= off) ? sdx[t - off] : 0u;
        __syncthreads();
        sdx[t] += y;
        __syncthreads();
      }
      u32 incl = sdx[t], excl = incl - part;
      if (k >= excl && k < incl) { sh_bin = (u32)t; sh_k = k - excl; }
      __syncthreads();
      pfx = (pfx << 8) | sh_bin;
      k = sh_k;
      __syncthreads();
    }
    if (t == 0) { if (which) khiA[g] = pfx; else kloA[g] = pfx; }
    __syncthreads();
  }
}

// K2: the 176 MB pass. Computes std (bit-exact), writes stdv. Handles ONLY the
// 4 std groups (20..23): register counters + 4-group LDS staging. Small state
// (4-element arrays SROA cleanly) -> no scratch spill.
__global__ __launch_bounds__(256) void k_std(const float* __restrict__ logits,
                                             float* __restrict__ stdv,
                                             const u32* __restrict__ kloA,
                                             const u32* __restrict__ khiA,
                                             u32* __restrict__ gcnt,
                                             u32* __restrict__ cntlo,
                                             u32* __restrict__ cand) {
  __shared__ u32 lcnt[4], lbase[4];
  __shared__ u32 lbuf[4 * LCAP_S];
  int t = threadIdx.x;
  if (t < 4) lcnt[t] = 0;
  __syncthreads();
  u32 klo[4], khi[4], cnt[4];
  #pragma unroll
  for (int j = 0; j < 4; ++j) { klo[j] = kloA[20+j]; khi[j] = khiA[20+j]; cnt[j] = 0; }
  const float4* L = (const float4*)logits;
  float4* S = (float4*)stdv;
  for (int q = blockIdx.x * 256 + t; q < NQ; q += gridDim.x * 256) {
    float4 v[10];
    #pragma unroll
    for (int b = 0; b < 10; ++b) v[b] = L[(size_t)b * NQ + q];
    float4 r;
    #pragma unroll
    for (int j = 0; j < 4; ++j) {
      float tmp[10];
      #pragma unroll
      for (int b = 0; b < 10; ++b) tmp[b] = ((const float*)&v[b])[j];
      float sdev = std10(tmp);
      ((float*)&r)[j] = sdev;
      u32 u = fkey(sdev);
      cnt[j] += (u < klo[j]) ? 1u : 0u;
      if (u >= klo[j] && u < khi[j]) {
        u32 p = atomicAdd(&lcnt[j], 1u);
        if (p < LCAP_S) lbuf[j * LCAP_S + p] = u;
        else { u32 gp = atomicAdd(&gcnt[20+j], 1u); if (gp < CAP) cand[(size_t)(20+j) * CAP + gp] = u; }
      }
    }
    nt_store4(&S[q], r);
  }
  #pragma unroll
  for (int j = 0; j < 4; ++j) {
    int c = (int)cnt[j];
    #pragma unroll
    for (int off = 32; off > 0; off >>= 1) c += __shfl_down(c, off, 64);
    if ((t & 63) == 0 && c) atomicAdd(&cntlo[20+j], (u32)c);
  }
  __syncthreads();
  if (t < 4) {
    u32 cnum = lcnt[t];
    if (cnum > LCAP_S) cnum = LCAP_S;
    lbase[t] = cnum ? atomicAdd(&gcnt[20+t], cnum) : 0u;
    lcnt[t] = cnum;
  }
  __syncthreads();
  #pragma unroll
  for (int j = 0; j < 4; ++j) {
    u32 cnum = lcnt[j], base = lbase[j];
    for (u32 i = t; i < cnum; i += 256) {
      u32 idx = base + i;
      if (idx < CAP) cand[(size_t)(20+j) * CAP + idx] = lbuf[j * LCAP_S + i];
    }
  }
}

// K3: logit-group count+compact, one b-slice (4 groups) per block. 80 MB read.
__global__ __launch_bounds__(256) void k_cnt(const float* __restrict__ logits,
                                             const u32* __restrict__ kloA,
                                             const u32* __restrict__ khiA,
                                             u32* __restrict__ gcnt,
                                             u32* __restrict__ cntlo,
                                             u32* __restrict__ cand) {
  __shared__ u32 lcnt[4], lbase[4];
  __shared__ u32 lbuf[4 * LCAP_C];
  int t = threadIdx.x;
  int b = blockIdx.x / BPS_C, r = blockIdx.x % BPS_C, gb = b * 4;
  if (t < 4) lcnt[t] = 0;
  __syncthreads();
  u32 klo[4], khi[4], cnt[4];
  #pragma unroll
  for (int j = 0; j < 4; ++j) { klo[j] = kloA[gb+j]; khi[j] = khiA[gb+j]; cnt[j] = 0; }
  const float4* src = (const float4*)logits + (size_t)b * NQ;
  for (int q = r * 256 + t; q < NQ; q += BPS_C * 256) {
    float4 v = src[q];
    #pragma unroll
    for (int j = 0; j < 4; ++j) {
      u32 u = fkey(((const float*)&v)[j]);
      cnt[j] += (u < klo[j]) ? 1u : 0u;
      if (u >= klo[j] && u < khi[j]) {
        u32 p = atomicAdd(&lcnt[j], 1u);
        if (p < LCAP_C) lbuf[j * LCAP_C + p] = u;
        else { u32 gp = atomicAdd(&gcnt[gb+j], 1u); if (gp < CAP) cand[(size_t)(gb+j) * CAP + gp] = u; }
      }
    }
  }
  #pragma unroll
  for (int j = 0; j < 4; ++j) {
    int c = (int)cnt[j];
    #pragma unroll
    for (int off = 32; off > 0; off >>= 1) c += __shfl_down(c, off, 64);
    if ((t & 63) == 0 && c) atomicAdd(&cntlo[gb+j], (u32)c);
  }
  __syncthreads();
  if (t < 4) {
    u32 cnum = lcnt[t];
    if (cnum > LCAP_C) cnum = LCAP_C;
    lbase[t] = cnum ? atomicAdd(&gcnt[gb+t], cnum) : 0u;
    lcnt[t] = cnum;
  }
  __syncthreads();
  #pragma unroll
  for (int j = 0; j < 4; ++j) {
    u32 cnum = lcnt[j], base = lbase[j];
    for (u32 i = t; i < cnum; i += 256) {
      u32 idx = base + i;
      if (idx < CAP) cand[(size_t)(gb+j) * CAP + idx] = lbuf[j * LCAP_C + i];
    }
  }
}

// K4: exact radix select of rank (KRANK - cntlo) among compacted candidates.
// (correctness-proven round 2)
__global__ __launch_bounds__(256) void k_sel(const u32* __restrict__ cand,
                                             const u32* __restrict__ gcnt,
                                             const u32* __restrict__ cntlo,
                                             const u32* __restrict__ kloA,
                                             const u32* __restrict__ khiA,
                                             float* __restrict__ selval,
                                             u32* __restrict__ flag) {
  int g = blockIdx.x, t = threadIdx.x;
  u32 n = gcnt[g];
  u32 k = KRANK - cntlo[g];      // underflow -> huge -> caught below
  if (n == 0 || n > CAP || k >= n) { if (t == 0) flag[g] = 1; return; }
  u32 lo = kloA[g], hi1 = khiA[g] - 1u;
  u32 xx = lo ^ hi1;
  int hb = xx ? (31 - __clz((int)xx)) : 0;
  int startRnd = 3 - (hb >> 3);
  __shared__ u32 hist[256], sdx[256];
  __shared__ u32 sh_bin, sh_k;
  const u32* c = cand + (size_t)g * CAP;
  u32 pfx = (startRnd == 0) ? 0u : (lo >> (32 - 8 * startRnd));
  for (int rnd = startRnd; rnd < 4; ++rnd) {
    int sh = 24 - 8 * rnd;
    hist[t] = 0;
    __syncthreads();
    for (u32 i = t; i < n; i += 256) {
      u32 u = c[i];
      if (rnd == 0 || (u >> (sh + 8)) == pfx)
        atomicAdd(&hist[(u >> sh) & 255u], 1u);
    }
    __syncthreads();
    u32 part = hist[t];
    sdx[t] = part;
    __syncthreads();
    for (int off = 1; off < 256; off <<= 1) {
      u32 y = (t >= off) ? sdx[t - off] : 0u;
      __syncthreads();
      sdx[t] += y;
      __syncthreads();
    }
    u32 incl = sdx[t], excl = incl - part;
    if (k >= excl && k < incl) { sh_bin = (u32)t; sh_k = k - excl; }
    __syncthreads();
    pfx = (pfx << 8) | sh_bin;
    k = sh_k;
    __syncthreads();
  }
  if (t == 0) selval[g] = funkey(pfx);
}

// K5: correctness fallback — exact full-column radix select for any group
// whose bracket failed. Early-exits (never runs for random-normal data).
__global__ __launch_bounds__(256) void k_fallback(const float* __restrict__ logits,
                                                  const float* __restrict__ stdv,
                                                  const u32* __restrict__ flag,
                                                  float* __restrict__ selval) {
  int g = blockIdx.x, t = threadIdx.x;
  if (!flag[g]) return;
  const float* base = (g < 20) ? (logits + (size_t)(g >> 2) * NQ * 4 + (g & 3))
                               : (stdv + (g - 20));
  __shared__ u32 hist[256], sdx[256];
  __shared__ u32 sh_bin, sh_k;
  u32 pfx = 0, k = KRANK;
  for (int rnd = 0; rnd < 4; ++rnd) {
    int sh = 24 - 8 * rnd;
    hist[t] = 0;
    __syncthreads();
    for (int i = t; i < NQ; i += 256) {
      u32 u = fkey(base[(size_t)i * 4]);
      if (rnd == 0 || (u >> (sh + 8)) == pfx)
        atomicAdd(&hist[(u >> sh) & 255u], 1u);
    }
    __syncthreads();
    u32 part = hist[t];
    sdx[t] = part;
    __syncthreads();
    for (int off = 1; off < 256; off <<= 1) {
      u32 y = (t >= off) ? sdx[t - off] : 0u;
      __syncthreads();
      sdx[t] += y;
      __syncthreads();
    }
    u32 incl = sdx[t], excl = incl - part;
    if (k >= excl && k < incl) { sh_bin = (u32)t; sh_k = k - excl; }
    __syncthreads();
    pfx = (pfx << 8) | sh_bin;
    k = sh_k;
    __syncthreads();
  }
  if (t == 0) selval[g] = funkey(pfx);
}

// K6: fused mode + out + c. thr = max(med+1.96*std_med, med+delta/2).
__global__ __launch_bounds__(256) void k_final(const float* __restrict__ logits,
                                               const float* __restrict__ selval,
                                               const float* __restrict__ table,
                                               const float* __restrict__ dptr,
                                               float* __restrict__ out) {
  __shared__ float thr[20];
  __shared__ float4 tab[160];
  int t = threadIdx.x;
  if (t < 20) {
    float m  = selval[t];
    float sm = selval[20 + (t & 3)];
    float a = __fadd_rn(m, __fmul_rn(1.96f, sm));   // two roundings, no FMA
    float b = __fadd_rn(m, __fmul_rn(0.5f, *dptr));
    thr[t] = fmaxf(a, b);
  }
  if (t < 160) tab[t] = ((const float4*)table)[t];
  __syncthreads();
  const float4* L = (const float4*)logits;
  float4* O = (float4*)out;
  float4* C = O + 10 * NQ;
  for (int n = blockIdx.x * 256 + t; n < NQ; n += gridDim.x * 256) {
    int s0 = 0, s1 = 0, s2 = 0, s3 = 0;
    #pragma unroll
    for (int b = 0; b < 5; ++b) {
      float4 v = L[b * NQ + n];
      s0 += v.x >= thr[b*4+0];
      s1 += v.y >= thr[b*4+1];
      s2 += v.z >= thr[b*4+2];
      s3 += v.w >= thr[b*4+3];
    }
    int m0 = s0 >= 3, m1 = s1 >= 3, m2 = s2 >= 3, m3 = s3 >= 3;
    int pat = m0 | (m1 << 1) | (m2 << 2) | (m3 << 3);
    float4 cm = make_float4((float)m0, (float)m1, (float)m2, (float)m3);
    #pragma unroll
    for (int b = 0; b < 10; ++b) {
      nt_store4(&O[b * NQ + n], tab[pat * 10 + b]);
      nt_store4(&C[b * NQ + n], cm);
    }
  }
}

extern "C" void kernel_launch(void* const* d_in, const int* in_sizes, int n_in,
                              void* d_out, int out_size, void* d_ws, size_t ws_size,
                              hipStream_t stream) {
  const float* logits = (const float*)d_in[0];
  const float* x      = (const float*)d_in[1];
  const float* dptr   = (const float*)d_in[2];
  float* out = (float*)d_out;
  char* ws = (char*)d_ws;

  float* stdv   = (float*)(ws + OFF_STD);
  u32*   cand   = (u32*)(ws + OFF_CAND);
  u32*   klo    = (u32*)(ws + OFF_KLO);
  u32*   khi    = (u32*)(ws + OFF_KHI);
  u32*   gcnt   = (u32*)(ws + OFF_GCNT);
  u32*   cntlo  = (u32*)(ws + OFF_CNTLO);
  u32*   flag   = (u32*)(ws + OFF_FLAG);
  float* selval = (float*)(ws + OFF_SELVAL);
  float* table  = (float*)(ws + OFF_TABLE);

  hipMemsetAsync(ws + OFF_GCNT, 0, ZERO_BYTES, stream);

  k_table<<<dim3(1), dim3(192), 0, stream>>>(x, dptr, table);
  k_sample<<<dim3(24), dim3(256), 0, stream>>>(logits, klo, khi);
  k_std<<<dim3(1024), dim3(256), 0, stream>>>(logits, stdv, klo, khi, gcnt, cntlo, cand);
  k_cnt<<<dim3(5 * BPS_C), dim3(256), 0, stream>>>(logits, klo, khi, gcnt, cntlo, cand);
  k_sel<<<dim3(24), dim3(256), 0, stream>>>(cand, gcnt, cntlo, klo, khi, selval, flag);
  k_fallback<<<dim3(24), dim3(256), 0, stream>>>(logits, stdv, flag, selval);
  k_final<<<dim3(2048), dim3(256), 0, stream>>>(logits, selval, table, dptr, out);
}

// Round 6
// 1004.418 us; speedup vs baseline: 1.5062x; 1.0057x over previous
//
#include <hip/hip_runtime.h>
#include <math.h>

typedef unsigned int u32;
typedef unsigned long long u64;
typedef float f32x4 __attribute__((ext_vector_type(4)));

#define NQ     1000000
#define KRANK  499999u
#define NS     16384        // samples per group
#define RANK_LO 7680u       // 8192 - 512  (8-sigma bracket)
#define RANK_HI 8704u       // 8192 + 512
#define CAP    131072       // candidate capacity per group (expected ~62K)
#define LCAP_S 256          // k_std per-block LDS staging per std group (expect ~61)
#define LCAP_C 1024         // k_cnt per-block LDS staging per logit group (expect ~490)
#define CHUNK_STRIDE 15625
#define BPS_C  128          // blocks per slice in k_cnt

// ---- ws layout (bytes) ----
#define OFF_STD    0            // 4M floats = 16,000,000
#define OFF_CAND   16000000     // 24*131072*4 = 12,582,912 -> ends 28,582,912
#define OFF_KLO    28582912     // 24*4
#define OFF_KHI    28583008     // 24*4
#define OFF_GCNT   28583104     // 24*4 (zeroed)
#define OFF_CNTLO  28583200     // 24*4 (zeroed)
#define OFF_FLAG   28583296     // 24*4 (zeroed)
#define OFF_SELVAL 28583392     // 24*4
#define OFF_TABLE  28583488     // 640*4 = 2560 (16B aligned)
#define ZERO_BYTES 288          // gcnt + cntlo + flag (contiguous)

__device__ __forceinline__ u32 fkey(float x) {
  u32 b = __float_as_uint(x);
  return (b & 0x80000000u) ? ~b : (b | 0x80000000u);
}
__device__ __forceinline__ float funkey(u32 u) {
  u32 b = (u & 0x80000000u) ? (u & 0x7fffffffu) : ~u;
  return __uint_as_float(b);
}
__device__ __forceinline__ void nt_store4(float4* p, float4 v) {
  f32x4 w = {v.x, v.y, v.z, v.w};
  __builtin_nontemporal_store(w, (f32x4*)p);
}
// ddof=1 std over 10 values — identical op order everywhere it is used.
__device__ __forceinline__ float std10(const float* v) {
  float sum = 0.f;
  #pragma unroll
  for (int b = 0; b < 10; ++b) sum = __fadd_rn(sum, v[b]);
  float mean = __fdiv_rn(sum, 10.0f);
  float ssd = 0.f;
  #pragma unroll
  for (int b = 0; b < 10; ++b) {
    float d = __fsub_rn(v[b], mean);
    ssd = __fadd_rn(ssd, __fmul_rn(d, d));
  }
  return sqrtf(__fdiv_rn(ssd, 9.0f));
}

// K0: 16-pattern x 10-batch x 4 output table.
__global__ void k_table(const float* __restrict__ x, const float* __restrict__ dptr,
                        float* __restrict__ table) {
  int t = threadIdx.x;
  if (t >= 160) return;
  int pat = t / 10, b = t % 10;
  float delta = *dptr;
  float xs[4];
  xs[0] = 0.f; xs[1] = x[b*3]; xs[2] = x[b*3+1]; xs[3] = x[b*3+2];
  float dx[4];
  #pragma unroll
  for (int j = 0; j < 4; ++j) dx[j] = delta * (float)((pat >> j) & 1) + xs[j];
  #pragma unroll
  for (int i = 0; i < 4; ++i) {
    float m = -1e30f;
    #pragma unroll
    for (int j = 0; j < 4; ++j) if (j != i) m = fmaxf(m, dx[j]);
    float ssum = 0.f;
    #pragma unroll
    for (int j = 0; j < 4; ++j) if (j != i) ssum += expf(dx[j] - m);
    table[(pat*10 + b)*4 + i] = dx[i] - (logf(ssum) + m);
  }
}

// K1: pivot estimation from deterministic 16384-element sample per group.
// (correctness-proven round 2)
__global__ __launch_bounds__(256) void k_sample(const float* __restrict__ logits,
                                                u32* __restrict__ kloA,
                                                u32* __restrict__ khiA) {
  __shared__ u32 keys[NS];
  __shared__ u32 hist[256], sdx[256];
  __shared__ u32 sh_bin, sh_k;
  int g = blockIdx.x, t = threadIdx.x;
  if (g < 20) {
    int b = g >> 2, i = g & 3;
    const float* base = logits + (size_t)b * NQ * 4 + i;
    for (int s = t; s < NS; s += 256) {
      int n = (s >> 8) * CHUNK_STRIDE + (s & 255);
      keys[s] = fkey(base[(size_t)n * 4]);
    }
  } else {
    int i = g - 20;
    const float* base = logits + i;
    for (int s = t; s < NS; s += 256) {
      int n = (s >> 8) * CHUNK_STRIDE + (s & 255);
      float tmp[10];
      #pragma unroll
      for (int b = 0; b < 10; ++b) tmp[b] = base[((size_t)b * NQ + n) * 4];
      keys[s] = fkey(std10(tmp));
    }
  }
  __syncthreads();
  #pragma unroll
  for (int which = 0; which < 2; ++which) {
    u32 k = which ? RANK_HI : RANK_LO;
    u32 pfx = 0;
    for (int rnd = 0; rnd < 4; ++rnd) {
      int sh = 24 - 8 * rnd;
      hist[t] = 0;
      __syncthreads();
      for (int s = t; s < NS; s += 256) {
        u32 u = keys[s];
        if (rnd == 0 || (u >> (sh + 8)) == pfx)
          atomicAdd(&hist[(u >> sh) & 255u], 1u);
      }
      __syncthreads();
      u32 part = hist[t];
      sdx[t] = part;
      __syncthreads();
      for (int off = 1; off < 256; off <<= 1) {
        u32 y = (t >= off) ? sdx[t - off] : 0u;
        __syncthreads();
        sdx[t] += y;
        __syncthreads();
      }
      u32 incl = sdx[t], excl = incl - part;
      if (k >= excl && k < incl) { sh_bin = (u32)t; sh_k = k - excl; }
      __syncthreads();
      pfx = (pfx << 8) | sh_bin;
      k = sh_k;
      __syncthreads();
    }
    if (t == 0) { if (which) khiA[g] = pfx; else kloA[g] = pfx; }
    __syncthreads();
  }
}

// K2: the 176 MB pass. Computes std (bit-exact), writes stdv. Handles ONLY the
// 4 std groups (20..23). __launch_bounds__(256, 2): min 2 waves/EU raises the
// VGPR cap to ~256 so v[10] (40 floats) stays RESIDENT — round-5 counters
// showed hipcc's max-occupancy default (VGPR=32) spilled it to scratch
// (417 GB/s, VALUBusy 4.5%, 234 us).
__global__ __launch_bounds__(256, 2) void k_std(const float* __restrict__ logits,
                                                float* __restrict__ stdv,
                                                const u32* __restrict__ kloA,
                                                const u32* __restrict__ khiA,
                                                u32* __restrict__ gcnt,
                                                u32* __restrict__ cntlo,
                                                u32* __restrict__ cand) {
  __shared__ u32 lcnt[4], lbase[4];
  __shared__ u32 lbuf[4 * LCAP_S];
  int t = threadIdx.x;
  if (t < 4) lcnt[t] = 0;
  __syncthreads();
  u32 klo[4], khi[4], cnt[4];
  #pragma unroll
  for (int j = 0; j < 4; ++j) { klo[j] = kloA[20+j]; khi[j] = khiA[20+j]; cnt[j] = 0; }
  const float4* L = (const float4*)logits;
  float4* S = (float4*)stdv;
  for (int q = blockIdx.x * 256 + t; q < NQ; q += gridDim.x * 256) {
    float4 v[10];
    #pragma unroll
    for (int b = 0; b < 10; ++b) v[b] = L[(size_t)b * NQ + q];
    float4 r;
    #pragma unroll
    for (int j = 0; j < 4; ++j) {
      float tmp[10];
      #pragma unroll
      for (int b = 0; b < 10; ++b) tmp[b] = ((const float*)&v[b])[j];
      float sdev = std10(tmp);
      ((float*)&r)[j] = sdev;
      u32 u = fkey(sdev);
      cnt[j] += (u < klo[j]) ? 1u : 0u;
      if (u >= klo[j] && u < khi[j]) {
        u32 p = atomicAdd(&lcnt[j], 1u);
        if (p < LCAP_S) lbuf[j * LCAP_S + p] = u;
        else { u32 gp = atomicAdd(&gcnt[20+j], 1u); if (gp < CAP) cand[(size_t)(20+j) * CAP + gp] = u; }
      }
    }
    nt_store4(&S[q], r);
  }
  #pragma unroll
  for (int j = 0; j < 4; ++j) {
    int c = (int)cnt[j];
    #pragma unroll
    for (int off = 32; off > 0; off >>= 1) c += __shfl_down(c, off, 64);
    if ((t & 63) == 0 && c) atomicAdd(&cntlo[20+j], (u32)c);
  }
  __syncthreads();
  if (t < 4) {
    u32 cnum = lcnt[t];
    if (cnum > LCAP_S) cnum = LCAP_S;
    lbase[t] = cnum ? atomicAdd(&gcnt[20+t], cnum) : 0u;
    lcnt[t] = cnum;
  }
  __syncthreads();
  #pragma unroll
  for (int j = 0; j < 4; ++j) {
    u32 cnum = lcnt[j], base = lbase[j];
    for (u32 i = t; i < cnum; i += 256) {
      u32 idx = base + i;
      if (idx < CAP) cand[(size_t)(20+j) * CAP + idx] = lbuf[j * LCAP_S + i];
    }
  }
}

// K3: logit-group count+compact, one b-slice (4 groups) per block. 80 MB read.
__global__ __launch_bounds__(256) void k_cnt(const float* __restrict__ logits,
                                             const u32* __restrict__ kloA,
                                             const u32* __restrict__ khiA,
                                             u32* __restrict__ gcnt,
                                             u32* __restrict__ cntlo,
                                             u32* __restrict__ cand) {
  __shared__ u32 lcnt[4], lbase[4];
  __shared__ u32 lbuf[4 * LCAP_C];
  int t = threadIdx.x;
  int b = blockIdx.x / BPS_C, r = blockIdx.x % BPS_C, gb = b * 4;
  if (t < 4) lcnt[t] = 0;
  __syncthreads();
  u32 klo[4], khi[4], cnt[4];
  #pragma unroll
  for (int j = 0; j < 4; ++j) { klo[j] = kloA[gb+j]; khi[j] = khiA[gb+j]; cnt[j] = 0; }
  const float4* src = (const float4*)logits + (size_t)b * NQ;
  for (int q = r * 256 + t; q < NQ; q += BPS_C * 256) {
    float4 v = src[q];
    #pragma unroll
    for (int j = 0; j < 4; ++j) {
      u32 u = fkey(((const float*)&v)[j]);
      cnt[j] += (u < klo[j]) ? 1u : 0u;
      if (u >= klo[j] && u < khi[j]) {
        u32 p = atomicAdd(&lcnt[j], 1u);
        if (p < LCAP_C) lbuf[j * LCAP_C + p] = u;
        else { u32 gp = atomicAdd(&gcnt[gb+j], 1u); if (gp < CAP) cand[(size_t)(gb+j) * CAP + gp] = u; }
      }
    }
  }
  #pragma unroll
  for (int j = 0; j < 4; ++j) {
    int c = (int)cnt[j];
    #pragma unroll
    for (int off = 32; off > 0; off >>= 1) c += __shfl_down(c, off, 64);
    if ((t & 63) == 0 && c) atomicAdd(&cntlo[gb+j], (u32)c);
  }
  __syncthreads();
  if (t < 4) {
    u32 cnum = lcnt[t];
    if (cnum > LCAP_C) cnum = LCAP_C;
    lbase[t] = cnum ? atomicAdd(&gcnt[gb+t], cnum) : 0u;
    lcnt[t] = cnum;
  }
  __syncthreads();
  #pragma unroll
  for (int j = 0; j < 4; ++j) {
    u32 cnum = lcnt[j], base = lbase[j];
    for (u32 i = t; i < cnum; i += 256) {
      u32 idx = base + i;
      if (idx < CAP) cand[(size_t)(gb+j) * CAP + idx] = lbuf[j * LCAP_C + i];
    }
  }
}

// K4: exact radix select of rank (KRANK - cntlo) among compacted candidates.
// (correctness-proven round 2)
__global__ __launch_bounds__(256) void k_sel(const u32* __restrict__ cand,
                                             const u32* __restrict__ gcnt,
                                             const u32* __restrict__ cntlo,
                                             const u32* __restrict__ kloA,
                                             const u32* __restrict__ khiA,
                                             float* __restrict__ selval,
                                             u32* __restrict__ flag) {
  int g = blockIdx.x, t = threadIdx.x;
  u32 n = gcnt[g];
  u32 k = KRANK - cntlo[g];      // underflow -> huge -> caught below
  if (n == 0 || n > CAP || k >= n) { if (t == 0) flag[g] = 1; return; }
  u32 lo = kloA[g], hi1 = khiA[g] - 1u;
  u32 xx = lo ^ hi1;
  int hb = xx ? (31 - __clz((int)xx)) : 0;
  int startRnd = 3 - (hb >> 3);
  __shared__ u32 hist[256], sdx[256];
  __shared__ u32 sh_bin, sh_k;
  const u32* c = cand + (size_t)g * CAP;
  u32 pfx = (startRnd == 0) ? 0u : (lo >> (32 - 8 * startRnd));
  for (int rnd = startRnd; rnd < 4; ++rnd) {
    int sh = 24 - 8 * rnd;
    hist[t] = 0;
    __syncthreads();
    for (u32 i = t; i < n; i += 256) {
      u32 u = c[i];
      if (rnd == 0 || (u >> (sh + 8)) == pfx)
        atomicAdd(&hist[(u >> sh) & 255u], 1u);
    }
    __syncthreads();
    u32 part = hist[t];
    sdx[t] = part;
    __syncthreads();
    for (int off = 1; off < 256; off <<= 1) {
      u32 y = (t >= off) ? sdx[t - off] : 0u;
      __syncthreads();
      sdx[t] += y;
      __syncthreads();
    }
    u32 incl = sdx[t], excl = incl - part;
    if (k >= excl && k < incl) { sh_bin = (u32)t; sh_k = k - excl; }
    __syncthreads();
    pfx = (pfx << 8) | sh_bin;
    k = sh_k;
    __syncthreads();
  }
  if (t == 0) selval[g] = funkey(pfx);
}

// K5: correctness fallback — exact full-column radix select for any group
// whose bracket failed. Early-exits (never runs for random-normal data).
__global__ __launch_bounds__(256) void k_fallback(const float* __restrict__ logits,
                                                  const float* __restrict__ stdv,
                                                  const u32* __restrict__ flag,
                                                  float* __restrict__ selval) {
  int g = blockIdx.x, t = threadIdx.x;
  if (!flag[g]) return;
  const float* base = (g < 20) ? (logits + (size_t)(g >> 2) * NQ * 4 + (g & 3))
                               : (stdv + (g - 20));
  __shared__ u32 hist[256], sdx[256];
  __shared__ u32 sh_bin, sh_k;
  u32 pfx = 0, k = KRANK;
  for (int rnd = 0; rnd < 4; ++rnd) {
    int sh = 24 - 8 * rnd;
    hist[t] = 0;
    __syncthreads();
    for (int i = t; i < NQ; i += 256) {
      u32 u = fkey(base[(size_t)i * 4]);
      if (rnd == 0 || (u >> (sh + 8)) == pfx)
        atomicAdd(&hist[(u >> sh) & 255u], 1u);
    }
    __syncthreads();
    u32 part = hist[t];
    sdx[t] = part;
    __syncthreads();
    for (int off = 1; off < 256; off <<= 1) {
      u32 y = (t >= off) ? sdx[t - off] : 0u;
      __syncthreads();
      sdx[t] += y;
      __syncthreads();
    }
    u32 incl = sdx[t], excl = incl - part;
    if (k >= excl && k < incl) { sh_bin = (u32)t; sh_k = k - excl; }
    __syncthreads();
    pfx = (pfx << 8) | sh_bin;
    k = sh_k;
    __syncthreads();
  }
  if (t == 0) selval[g] = funkey(pfx);
}

// K6: fused mode + out + c. thr = max(med+1.96*std_med, med+delta/2).
__global__ __launch_bounds__(256) void k_final(const float* __restrict__ logits,
                                               const float* __restrict__ selval,
                                               const float* __restrict__ table,
                                               const float* __restrict__ dptr,
                                               float* __restrict__ out) {
  __shared__ float thr[20];
  __shared__ float4 tab[160];
  int t = threadIdx.x;
  if (t < 20) {
    float m  = selval[t];
    float sm = selval[20 + (t & 3)];
    float a = __fadd_rn(m, __fmul_rn(1.96f, sm));   // two roundings, no FMA
    float b = __fadd_rn(m, __fmul_rn(0.5f, *dptr));
    thr[t] = fmaxf(a, b);
  }
  if (t < 160) tab[t] = ((const float4*)table)[t];
  __syncthreads();
  const float4* L = (const float4*)logits;
  float4* O = (float4*)out;
  float4* C = O + 10 * NQ;
  for (int n = blockIdx.x * 256 + t; n < NQ; n += gridDim.x * 256) {
    int s0 = 0, s1 = 0, s2 = 0, s3 = 0;
    #pragma unroll
    for (int b = 0; b < 5; ++b) {
      float4 v = L[b * NQ + n];
      s0 += v.x >= thr[b*4+0];
      s1 += v.y >= thr[b*4+1];
      s2 += v.z >= thr[b*4+2];
      s3 += v.w >= thr[b*4+3];
    }
    int m0 = s0 >= 3, m1 = s1 >= 3, m2 = s2 >= 3, m3 = s3 >= 3;
    int pat = m0 | (m1 << 1) | (m2 << 2) | (m3 << 3);
    float4 cm = make_float4((float)m0, (float)m1, (float)m2, (float)m3);
    #pragma unroll
    for (int b = 0; b < 10; ++b) {
      nt_store4(&O[b * NQ + n], tab[pat * 10 + b]);
      nt_store4(&C[b * NQ + n], cm);
    }
  }
}

extern "C" void kernel_launch(void* const* d_in, const int* in_sizes, int n_in,
                              void* d_out, int out_size, void* d_ws, size_t ws_size,
                              hipStream_t stream) {
  const float* logits = (const float*)d_in[0];
  const float* x      = (const float*)d_in[1];
  const float* dptr   = (const float*)d_in[2];
  float* out = (float*)d_out;
  char* ws = (char*)d_ws;

  float* stdv   = (float*)(ws + OFF_STD);
  u32*   cand   = (u32*)(ws + OFF_CAND);
  u32*   klo    = (u32*)(ws + OFF_KLO);
  u32*   khi    = (u32*)(ws + OFF_KHI);
  u32*   gcnt   = (u32*)(ws + OFF_GCNT);
  u32*   cntlo  = (u32*)(ws + OFF_CNTLO);
  u32*   flag   = (u32*)(ws + OFF_FLAG);
  float* selval = (float*)(ws + OFF_SELVAL);
  float* table  = (float*)(ws + OFF_TABLE);

  hipMemsetAsync(ws + OFF_GCNT, 0, ZERO_BYTES, stream);

  k_table<<<dim3(1), dim3(192), 0, stream>>>(x, dptr, table);
  k_sample<<<dim3(24), dim3(256), 0, stream>>>(logits, klo, khi);
  k_std<<<dim3(1024), dim3(256), 0, stream>>>(logits, stdv, klo, khi, gcnt, cntlo, cand);
  k_cnt<<<dim3(5 * BPS_C), dim3(256), 0, stream>>>(logits, klo, khi, gcnt, cntlo, cand);
  k_sel<<<dim3(24), dim3(256), 0, stream>>>(cand, gcnt, cntlo, klo, khi, selval, flag);
  k_fallback<<<dim3(24), dim3(256), 0, stream>>>(logits, stdv, flag, selval);
  k_final<<<dim3(2048), dim3(256), 0, stream>>>(logits, selval, table, dptr, out);
}

// Round 7
// 999.708 us; speedup vs baseline: 1.5133x; 1.0047x over previous
//
#include <hip/hip_runtime.h>
#include <math.h>

typedef unsigned int u32;
typedef unsigned long long u64;
typedef float f32x4 __attribute__((ext_vector_type(4)));

#define NQ     1000000
#define KRANK  499999u
#define NS     16384        // samples per group
#define RANK_LO 7680u       // 8192 - 512  (8-sigma bracket)
#define RANK_HI 8704u       // 8192 + 512
#define CAP    131072       // candidate capacity per group (expected ~62K)
#define LCAP_S 256          // k_std per-block LDS staging per std group (expect ~61)
#define LCAP_C 1024         // k_cnt per-block LDS staging per logit group (expect ~490)
#define CHUNK_STRIDE 15625
#define BPS_C  128          // blocks per slice in k_cnt
#define SBLK   1024         // k_std grid

// ---- ws layout (bytes) ----
#define OFF_STD    0            // 4M floats = 16,000,000
#define OFF_CAND   16000000     // 24*131072*4 = 12,582,912 -> ends 28,582,912
#define OFF_KLO    28582912     // 24*4
#define OFF_KHI    28583008     // 24*4
#define OFF_GCNT   28583104     // 24*4 (zeroed)
#define OFF_CNTLO  28583200     // 24*4 (zeroed)
#define OFF_FLAG   28583296     // 24*4 (zeroed)
#define OFF_SELVAL 28583392     // 24*4
#define OFF_TABLE  28583488     // 640*4 = 2560 (16B aligned)
#define ZERO_BYTES 288          // gcnt + cntlo + flag (contiguous)

typedef const __attribute__((address_space(1))) void* gas_t;
typedef __attribute__((address_space(3))) void* las_t;
// global->LDS DMA, 16B per lane. LDS dest = wave-uniform base + lane*16 (m104).
__device__ __forceinline__ void g2lds16(const void* g, void* l) {
  __builtin_amdgcn_global_load_lds((gas_t)g, (las_t)l, 16, 0, 0);
}

__device__ __forceinline__ u32 fkey(float x) {
  u32 b = __float_as_uint(x);
  return (b & 0x80000000u) ? ~b : (b | 0x80000000u);
}
__device__ __forceinline__ float funkey(u32 u) {
  u32 b = (u & 0x80000000u) ? (u & 0x7fffffffu) : ~u;
  return __uint_as_float(b);
}
__device__ __forceinline__ void nt_store4(float4* p, float4 v) {
  f32x4 w = {v.x, v.y, v.z, v.w};
  __builtin_nontemporal_store(w, (f32x4*)p);
}
// ddof=1 std over 10 values — identical op order everywhere it is used.
__device__ __forceinline__ float std10(const float* v) {
  float sum = 0.f;
  #pragma unroll
  for (int b = 0; b < 10; ++b) sum = __fadd_rn(sum, v[b]);
  float mean = __fdiv_rn(sum, 10.0f);
  float ssd = 0.f;
  #pragma unroll
  for (int b = 0; b < 10; ++b) {
    float d = __fsub_rn(v[b], mean);
    ssd = __fadd_rn(ssd, __fmul_rn(d, d));
  }
  return sqrtf(__fdiv_rn(ssd, 9.0f));
}

// K0: 16-pattern x 10-batch x 4 output table.
__global__ void k_table(const float* __restrict__ x, const float* __restrict__ dptr,
                        float* __restrict__ table) {
  int t = threadIdx.x;
  if (t >= 160) return;
  int pat = t / 10, b = t % 10;
  float delta = *dptr;
  float xs[4];
  xs[0] = 0.f; xs[1] = x[b*3]; xs[2] = x[b*3+1]; xs[3] = x[b*3+2];
  float dx[4];
  #pragma unroll
  for (int j = 0; j < 4; ++j) dx[j] = delta * (float)((pat >> j) & 1) + xs[j];
  #pragma unroll
  for (int i = 0; i < 4; ++i) {
    float m = -1e30f;
    #pragma unroll
    for (int j = 0; j < 4; ++j) if (j != i) m = fmaxf(m, dx[j]);
    float ssum = 0.f;
    #pragma unroll
    for (int j = 0; j < 4; ++j) if (j != i) ssum += expf(dx[j] - m);
    table[(pat*10 + b)*4 + i] = dx[i] - (logf(ssum) + m);
  }
}

// K1: pivot estimation from deterministic 16384-element sample per group.
// (correctness-proven round 2)
__global__ __launch_bounds__(256) void k_sample(const float* __restrict__ logits,
                                                u32* __restrict__ kloA,
                                                u32* __restrict__ khiA) {
  __shared__ u32 keys[NS];
  __shared__ u32 hist[256], sdx[256];
  __shared__ u32 sh_bin, sh_k;
  int g = blockIdx.x, t = threadIdx.x;
  if (g < 20) {
    int b = g >> 2, i = g & 3;
    const float* base = logits + (size_t)b * NQ * 4 + i;
    for (int s = t; s < NS; s += 256) {
      int n = (s >> 8) * CHUNK_STRIDE + (s & 255);
      keys[s] = fkey(base[(size_t)n * 4]);
    }
  } else {
    int i = g - 20;
    const float* base = logits + i;
    for (int s = t; s < NS; s += 256) {
      int n = (s >> 8) * CHUNK_STRIDE + (s & 255);
      float tmp[10];
      #pragma unroll
      for (int b = 0; b < 10; ++b) tmp[b] = base[((size_t)b * NQ + n) * 4];
      keys[s] = fkey(std10(tmp));
    }
  }
  __syncthreads();
  #pragma unroll
  for (int which = 0; which < 2; ++which) {
    u32 k = which ? RANK_HI : RANK_LO;
    u32 pfx = 0;
    for (int rnd = 0; rnd < 4; ++rnd) {
      int sh = 24 - 8 * rnd;
      hist[t] = 0;
      __syncthreads();
      for (int s = t; s < NS; s += 256) {
        u32 u = keys[s];
        if (rnd == 0 || (u >> (sh + 8)) == pfx)
          atomicAdd(&hist[(u >> sh) & 255u], 1u);
      }
      __syncthreads();
      u32 part = hist[t];
      sdx[t] = part;
      __syncthreads();
      for (int off = 1; off < 256; off <<= 1) {
        u32 y = (t >= off) ? sdx[t - off] : 0u;
        __syncthreads();
        sdx[t] += y;
        __syncthreads();
      }
      u32 incl = sdx[t], excl = incl - part;
      if (k >= excl && k < incl) { sh_bin = (u32)t; sh_k = k - excl; }
      __syncthreads();
      pfx = (pfx << 8) | sh_bin;
      k = sh_k;
      __syncthreads();
    }
    if (t == 0) { if (which) khiA[g] = pfx; else kloA[g] = pfx; }
    __syncthreads();
  }
}

// K2: the 176 MB pass, restructured after r5/r6 counters (VGPR=32, 417 GB/s,
// VALUBusy 4.5% — allocator refuses a 40-float live set; launch_bounds no-op).
// Structural fix: global->LDS DMA staging (no VGPR round trip), then TWO
// vector passes over the LDS tile (sum, then ssd) so only ~16 floats are ever
// live. Each wave reads only its own 64-slot slice -> no __syncthreads in the
// loop. asm memory clobber between passes blocks CSE from re-materializing the
// 40-float live set. Per-component op order identical to std10 -> bit-exact.
__global__ __launch_bounds__(256) void k_std(const float* __restrict__ logits,
                                             float* __restrict__ stdv,
                                             const u32* __restrict__ kloA,
                                             const u32* __restrict__ khiA,
                                             u32* __restrict__ gcnt,
                                             u32* __restrict__ cntlo,
                                             u32* __restrict__ cand) {
  __shared__ float4 tile[10 * 256];      // 40 KB DMA staging
  __shared__ u32 lcnt[4], lbase[4];
  __shared__ u32 lbuf[4 * LCAP_S];
  int t = threadIdx.x;
  if (t < 4) lcnt[t] = 0;
  __syncthreads();
  u32 klo[4], khi[4], cnt[4];
  #pragma unroll
  for (int j = 0; j < 4; ++j) { klo[j] = kloA[20+j]; khi[j] = khiA[20+j]; cnt[j] = 0; }
  const float4* L = (const float4*)logits;
  float4* S = (float4*)stdv;
  int wbase = t & ~63;                   // wave-uniform LDS slot base
  for (int base = blockIdx.x * 256; base < NQ; base += SBLK * 256) {
    int q = base + t;
    int qs = (q < NQ) ? q : 0;           // clamp source (per-lane addr is legal)
    #pragma unroll
    for (int b = 0; b < 10; ++b)
      g2lds16(&L[(size_t)b * NQ + qs], &tile[b * 256 + wbase]);
    asm volatile("s_waitcnt vmcnt(0)" ::: "memory");
    // pass 1: vector sum over b (same add order as std10)
    float4 sum = make_float4(0.f, 0.f, 0.f, 0.f);
    #pragma unroll
    for (int b = 0; b < 10; ++b) {
      float4 xv = tile[b * 256 + t];
      sum.x = __fadd_rn(sum.x, xv.x); sum.y = __fadd_rn(sum.y, xv.y);
      sum.z = __fadd_rn(sum.z, xv.z); sum.w = __fadd_rn(sum.w, xv.w);
    }
    float4 mean;
    mean.x = __fdiv_rn(sum.x, 10.0f); mean.y = __fdiv_rn(sum.y, 10.0f);
    mean.z = __fdiv_rn(sum.z, 10.0f); mean.w = __fdiv_rn(sum.w, 10.0f);
    asm volatile("" ::: "memory");       // block CSE of the tile reads
    // pass 2: vector ssd over b (same order)
    float4 ssd = make_float4(0.f, 0.f, 0.f, 0.f);
    #pragma unroll
    for (int b = 0; b < 10; ++b) {
      float4 xv = tile[b * 256 + t];
      float dx = __fsub_rn(xv.x, mean.x); ssd.x = __fadd_rn(ssd.x, __fmul_rn(dx, dx));
      float dy = __fsub_rn(xv.y, mean.y); ssd.y = __fadd_rn(ssd.y, __fmul_rn(dy, dy));
      float dz = __fsub_rn(xv.z, mean.z); ssd.z = __fadd_rn(ssd.z, __fmul_rn(dz, dz));
      float dw = __fsub_rn(xv.w, mean.w); ssd.w = __fadd_rn(ssd.w, __fmul_rn(dw, dw));
    }
    float4 r;
    r.x = sqrtf(__fdiv_rn(ssd.x, 9.0f)); r.y = sqrtf(__fdiv_rn(ssd.y, 9.0f));
    r.z = sqrtf(__fdiv_rn(ssd.z, 9.0f)); r.w = sqrtf(__fdiv_rn(ssd.w, 9.0f));
    if (q < NQ) {
      nt_store4(&S[q], r);
      #pragma unroll
      for (int j = 0; j < 4; ++j) {
        u32 u = fkey(((const float*)&r)[j]);
        cnt[j] += (u < klo[j]) ? 1u : 0u;
        if (u >= klo[j] && u < khi[j]) {
          u32 p = atomicAdd(&lcnt[j], 1u);
          if (p < LCAP_S) lbuf[j * LCAP_S + p] = u;
          else { u32 gp = atomicAdd(&gcnt[20+j], 1u); if (gp < CAP) cand[(size_t)(20+j) * CAP + gp] = u; }
        }
      }
    }
  }
  #pragma unroll
  for (int j = 0; j < 4; ++j) {
    int c = (int)cnt[j];
    #pragma unroll
    for (int off = 32; off > 0; off >>= 1) c += __shfl_down(c, off, 64);
    if ((t & 63) == 0 && c) atomicAdd(&cntlo[20+j], (u32)c);
  }
  __syncthreads();
  if (t < 4) {
    u32 cnum = lcnt[t];
    if (cnum > LCAP_S) cnum = LCAP_S;
    lbase[t] = cnum ? atomicAdd(&gcnt[20+t], cnum) : 0u;
    lcnt[t] = cnum;
  }
  __syncthreads();
  #pragma unroll
  for (int j = 0; j < 4; ++j) {
    u32 cnum = lcnt[j], base = lbase[j];
    for (u32 i = t; i < cnum; i += 256) {
      u32 idx = base + i;
      if (idx < CAP) cand[(size_t)(20+j) * CAP + idx] = lbuf[j * LCAP_S + i];
    }
  }
}

// K3: logit-group count+compact, one b-slice (4 groups) per block. 80 MB read.
__global__ __launch_bounds__(256) void k_cnt(const float* __restrict__ logits,
                                             const u32* __restrict__ kloA,
                                             const u32* __restrict__ khiA,
                                             u32* __restrict__ gcnt,
                                             u32* __restrict__ cntlo,
                                             u32* __restrict__ cand) {
  __shared__ u32 lcnt[4], lbase[4];
  __shared__ u32 lbuf[4 * LCAP_C];
  int t = threadIdx.x;
  int b = blockIdx.x / BPS_C, r = blockIdx.x % BPS_C, gb = b * 4;
  if (t < 4) lcnt[t] = 0;
  __syncthreads();
  u32 klo[4], khi[4], cnt[4];
  #pragma unroll
  for (int j = 0; j < 4; ++j) { klo[j] = kloA[gb+j]; khi[j] = khiA[gb+j]; cnt[j] = 0; }
  const float4* src = (const float4*)logits + (size_t)b * NQ;
  for (int q = r * 256 + t; q < NQ; q += BPS_C * 256) {
    float4 v = src[q];
    #pragma unroll
    for (int j = 0; j < 4; ++j) {
      u32 u = fkey(((const float*)&v)[j]);
      cnt[j] += (u < klo[j]) ? 1u : 0u;
      if (u >= klo[j] && u < khi[j]) {
        u32 p = atomicAdd(&lcnt[j], 1u);
        if (p < LCAP_C) lbuf[j * LCAP_C + p] = u;
        else { u32 gp = atomicAdd(&gcnt[gb+j], 1u); if (gp < CAP) cand[(size_t)(gb+j) * CAP + gp] = u; }
      }
    }
  }
  #pragma unroll
  for (int j = 0; j < 4; ++j) {
    int c = (int)cnt[j];
    #pragma unroll
    for (int off = 32; off > 0; off >>= 1) c += __shfl_down(c, off, 64);
    if ((t & 63) == 0 && c) atomicAdd(&cntlo[gb+j], (u32)c);
  }
  __syncthreads();
  if (t < 4) {
    u32 cnum = lcnt[t];
    if (cnum > LCAP_C) cnum = LCAP_C;
    lbase[t] = cnum ? atomicAdd(&gcnt[gb+t], cnum) : 0u;
    lcnt[t] = cnum;
  }
  __syncthreads();
  #pragma unroll
  for (int j = 0; j < 4; ++j) {
    u32 cnum = lcnt[j], base = lbase[j];
    for (u32 i = t; i < cnum; i += 256) {
      u32 idx = base + i;
      if (idx < CAP) cand[(size_t)(gb+j) * CAP + idx] = lbuf[j * LCAP_C + i];
    }
  }
}

// K4: exact radix select of rank (KRANK - cntlo) among compacted candidates.
// (correctness-proven round 2)
__global__ __launch_bounds__(256) void k_sel(const u32* __restrict__ cand,
                                             const u32* __restrict__ gcnt,
                                             const u32* __restrict__ cntlo,
                                             const u32* __restrict__ kloA,
                                             const u32* __restrict__ khiA,
                                             float* __restrict__ selval,
                                             u32* __restrict__ flag) {
  int g = blockIdx.x, t = threadIdx.x;
  u32 n = gcnt[g];
  u32 k = KRANK - cntlo[g];      // underflow -> huge -> caught below
  if (n == 0 || n > CAP || k >= n) { if (t == 0) flag[g] = 1; return; }
  u32 lo = kloA[g], hi1 = khiA[g] - 1u;
  u32 xx = lo ^ hi1;
  int hb = xx ? (31 - __clz((int)xx)) : 0;
  int startRnd = 3 - (hb >> 3);
  __shared__ u32 hist[256], sdx[256];
  __shared__ u32 sh_bin, sh_k;
  const u32* c = cand + (size_t)g * CAP;
  u32 pfx = (startRnd == 0) ? 0u : (lo >> (32 - 8 * startRnd));
  for (int rnd = startRnd; rnd < 4; ++rnd) {
    int sh = 24 - 8 * rnd;
    hist[t] = 0;
    __syncthreads();
    for (u32 i = t; i < n; i += 256) {
      u32 u = c[i];
      if (rnd == 0 || (u >> (sh + 8)) == pfx)
        atomicAdd(&hist[(u >> sh) & 255u], 1u);
    }
    __syncthreads();
    u32 part = hist[t];
    sdx[t] = part;
    __syncthreads();
    for (int off = 1; off < 256; off <<= 1) {
      u32 y = (t >= off) ? sdx[t - off] : 0u;
      __syncthreads();
      sdx[t] += y;
      __syncthreads();
    }
    u32 incl = sdx[t], excl = incl - part;
    if (k >= excl && k < incl) { sh_bin = (u32)t; sh_k = k - excl; }
    __syncthreads();
    pfx = (pfx << 8) | sh_bin;
    k = sh_k;
    __syncthreads();
  }
  if (t == 0) selval[g] = funkey(pfx);
}

// K5: correctness fallback — exact full-column radix select for any group
// whose bracket failed. Early-exits (never runs for random-normal data).
__global__ __launch_bounds__(256) void k_fallback(const float* __restrict__ logits,
                                                  const float* __restrict__ stdv,
                                                  const u32* __restrict__ flag,
                                                  float* __restrict__ selval) {
  int g = blockIdx.x, t = threadIdx.x;
  if (!flag[g]) return;
  const float* base = (g < 20) ? (logits + (size_t)(g >> 2) * NQ * 4 + (g & 3))
                               : (stdv + (g - 20));
  __shared__ u32 hist[256], sdx[256];
  __shared__ u32 sh_bin, sh_k;
  u32 pfx = 0, k = KRANK;
  for (int rnd = 0; rnd < 4; ++rnd) {
    int sh = 24 - 8 * rnd;
    hist[t] = 0;
    __syncthreads();
    for (int i = t; i < NQ; i += 256) {
      u32 u = fkey(base[(size_t)i * 4]);
      if (rnd == 0 || (u >> (sh + 8)) == pfx)
        atomicAdd(&hist[(u >> sh) & 255u], 1u);
    }
    __syncthreads();
    u32 part = hist[t];
    sdx[t] = part;
    __syncthreads();
    for (int off = 1; off < 256; off <<= 1) {
      u32 y = (t >= off) ? sdx[t - off] : 0u;
      __syncthreads();
      sdx[t] += y;
      __syncthreads();
    }
    u32 incl = sdx[t], excl = incl - part;
    if (k >= excl && k < incl) { sh_bin = (u32)t; sh_k = k - excl; }
    __syncthreads();
    pfx = (pfx << 8) | sh_bin;
    k = sh_k;
    __syncthreads();
  }
  if (t == 0) selval[g] = funkey(pfx);
}

// K6: fused mode + out + c. thr = max(med+1.96*std_med, med+delta/2).
__global__ __launch_bounds__(256) void k_final(const float* __restrict__ logits,
                                               const float* __restrict__ selval,
                                               const float* __restrict__ table,
                                               const float* __restrict__ dptr,
                                               float* __restrict__ out) {
  __shared__ float thr[20];
  __shared__ float4 tab[160];
  int t = threadIdx.x;
  if (t < 20) {
    float m  = selval[t];
    float sm = selval[20 + (t & 3)];
    float a = __fadd_rn(m, __fmul_rn(1.96f, sm));   // two roundings, no FMA
    float b = __fadd_rn(m, __fmul_rn(0.5f, *dptr));
    thr[t] = fmaxf(a, b);
  }
  if (t < 160) tab[t] = ((const float4*)table)[t];
  __syncthreads();
  const float4* L = (const float4*)logits;
  float4* O = (float4*)out;
  float4* C = O + 10 * NQ;
  for (int n = blockIdx.x * 256 + t; n < NQ; n += gridDim.x * 256) {
    int s0 = 0, s1 = 0, s2 = 0, s3 = 0;
    #pragma unroll
    for (int b = 0; b < 5; ++b) {
      float4 v = L[b * NQ + n];
      s0 += v.x >= thr[b*4+0];
      s1 += v.y >= thr[b*4+1];
      s2 += v.z >= thr[b*4+2];
      s3 += v.w >= thr[b*4+3];
    }
    int m0 = s0 >= 3, m1 = s1 >= 3, m2 = s2 >= 3, m3 = s3 >= 3;
    int pat = m0 | (m1 << 1) | (m2 << 2) | (m3 << 3);
    float4 cm = make_float4((float)m0, (float)m1, (float)m2, (float)m3);
    #pragma unroll
    for (int b = 0; b < 10; ++b) {
      nt_store4(&O[b * NQ + n], tab[pat * 10 + b]);
      nt_store4(&C[b * NQ + n], cm);
    }
  }
}

extern "C" void kernel_launch(void* const* d_in, const int* in_sizes, int n_in,
                              void* d_out, int out_size, void* d_ws, size_t ws_size,
                              hipStream_t stream) {
  const float* logits = (const float*)d_in[0];
  const float* x      = (const float*)d_in[1];
  const float* dptr   = (const float*)d_in[2];
  float* out = (float*)d_out;
  char* ws = (char*)d_ws;

  float* stdv   = (float*)(ws + OFF_STD);
  u32*   cand   = (u32*)(ws + OFF_CAND);
  u32*   klo    = (u32*)(ws + OFF_KLO);
  u32*   khi    = (u32*)(ws + OFF_KHI);
  u32*   gcnt   = (u32*)(ws + OFF_GCNT);
  u32*   cntlo  = (u32*)(ws + OFF_CNTLO);
  u32*   flag   = (u32*)(ws + OFF_FLAG);
  float* selval = (float*)(ws + OFF_SELVAL);
  float* table  = (float*)(ws + OFF_TABLE);

  hipMemsetAsync(ws + OFF_GCNT, 0, ZERO_BYTES, stream);

  k_table<<<dim3(1), dim3(192), 0, stream>>>(x, dptr, table);
  k_sample<<<dim3(24), dim3(256), 0, stream>>>(logits, klo, khi);
  k_std<<<dim3(SBLK), dim3(256), 0, stream>>>(logits, stdv, klo, khi, gcnt, cntlo, cand);
  k_cnt<<<dim3(5 * BPS_C), dim3(256), 0, stream>>>(logits, klo, khi, gcnt, cntlo, cand);
  k_sel<<<dim3(24), dim3(256), 0, stream>>>(cand, gcnt, cntlo, klo, khi, selval, flag);
  k_fallback<<<dim3(24), dim3(256), 0, stream>>>(logits, stdv, flag, selval);
  k_final<<<dim3(2048), dim3(256), 0, stream>>>(logits, selval, table, dptr, out);
}